// Round 9
// baseline (155.191 us; speedup 1.0000x reference)
//
#include <hip/hip_runtime.h>
#include <stdint.h>

#define DM 1024
#define LS 2048
#define RMS_EPS 1.1920928955078125e-07f
#define S2 0.0029296875f   // BC_SCALE^2 = 3/1024, exact in fp32

typedef __attribute__((ext_vector_type(8))) short bf16x8;
typedef __attribute__((ext_vector_type(4))) float f32x4;

__device__ __forceinline__ unsigned short f2bf(float f) {
  uint32_t u = __builtin_bit_cast(uint32_t, f);
  u += 0x7FFFu + ((u >> 16) & 1u);   // round-to-nearest-even
  return (unsigned short)(u >> 16);
}

// ---------------------------------------------------------------------------
// K0: pack B (64x1024) and C (64x1024) fp32 -> stacked bf16 [128][1024]
// ---------------------------------------------------------------------------
__global__ __launch_bounds__(256) void k0_prep(const float* __restrict__ B,
                                               const float* __restrict__ C,
                                               unsigned short* __restrict__ Bbf) {
  int i4 = blockIdx.x * 256 + threadIdx.x;          // 0..32767 float4s
  const float4* src = (i4 < 16384) ? (const float4*)B : (const float4*)C;
  float4 v = src[i4 & 16383];
  ushort4 o;
  o.x = f2bf(v.x); o.y = f2bf(v.y); o.z = f2bf(v.z); o.w = f2bf(v.w);
  ((ushort4*)Bbf)[i4] = o;
}

// ---------------------------------------------------------------------------
// K1 (R0-proven, verbatim): BuCuT[b][l][128] = ([B;C] @ u[b])^T, 16x16x32 MFMA.
// grid (128,4)=512 blocks (2/CU), block 256 (4 waves).  32 KB tile, ONE
// pre-compute barrier, free-run 32-it MFMA loop with global Bbf A-frags.
// ---------------------------------------------------------------------------
__global__ __launch_bounds__(256) void k1_gemm(const float* __restrict__ u,
                                               const unsigned short* __restrict__ Bbf,
                                               float* __restrict__ BuCuT) {
  const int b    = blockIdx.y;
  const int l0   = blockIdx.x * 16;
  const int lane = threadIdx.x & 63;
  const int w    = threadIdx.x >> 6;
  const float* ub = u + (size_t)b * DM * LS;

  __shared__ bf16x8 tile[128][16];   // 32 KB

  { // ---- stage: wave w covers k in [256w, 256w+256) ----
    const int lq = lane & 3;          // col quad: cols 4lq..4lq+3
    const int kg = lane >> 2;         // 0..15 -> 16 k-rows each
    const int kbase = 256 * w + 16 * kg;
    #pragma unroll
    for (int h = 0; h < 2; ++h) {
      float4 vv[8];
      #pragma unroll
      for (int r = 0; r < 8; ++r)
        vv[r] = *(const float4*)(ub + (size_t)(kbase + 8*h + r) * LS + l0 + 4*lq);
      const int k8 = 32*w + 2*kg + h;
      #pragma unroll
      for (int c = 0; c < 4; ++c) {
        union { bf16x8 v; unsigned short s[8]; } t;
        #pragma unroll
        for (int r = 0; r < 8; ++r) t.s[r] = f2bf(((const float*)&vv[r])[c]);
        tile[k8][(4*lq + c) ^ (k8 & 3)] = t.v;
      }
    }
  }
  __syncthreads();

  // ---- compute: M=32 rows per wave, N=16, K=1024 ----
  const int n = lane & 15;
  const int q = lane >> 4;
  f32x4 acc[2] = {};
  #pragma unroll 4
  for (int it = 0; it < 32; ++it) {
    bf16x8 bfrag = tile[4*it + q][n ^ q];
    #pragma unroll
    for (int rt = 0; rt < 2; ++rt) {
      int row = 32*w + 16*rt + n;
      bf16x8 a = *(const bf16x8*)(Bbf + (size_t)row * DM + 32*it + 8*q);
      acc[rt] = __builtin_amdgcn_mfma_f32_16x16x32_bf16(a, bfrag, acc[rt], 0, 0, 0);
    }
  }

  float* ob = BuCuT + (size_t)b * LS * 128;
  #pragma unroll
  for (int rt = 0; rt < 2; ++rt) {
    int col = l0 + n;                 // C/D: col = lane&15
    int row = 32*w + 16*rt + 4*q;     // row = 4*(lane>>4) + reg
    *(f32x4*)(ob + (size_t)col * 128 + row) = acc[rt];
  }
}

// ---------------------------------------------------------------------------
// KWX: Kw[b][t][16] from BuCuT (L2-hot: just written, same-XCD for own tile).
// grid (128,4)=512 blocks, block 256.  Kw[t][j] = S2*sum_n Cu[t][n]A^j[n]
// Bu[t-j][n] -- v6/kc-v4-proven recurrence, reads global fp32 BuCuT.
// Thread (t:16, p:16); shfl-xor reduce over p; 1 KB coalesced write.
// ---------------------------------------------------------------------------
__global__ __launch_bounds__(256) void kwx(const float* __restrict__ BuCuT,
                                           const float* __restrict__ A,
                                           float* __restrict__ Kwg) {
  const int b  = blockIdx.y;
  const int t0 = blockIdx.x * 16;
  const int tid = threadIdx.x;

  __shared__ float KwS[16][20];

  {
    const int t = tid >> 4, p = tid & 15;
    const float* bb = BuCuT + (size_t)b * LS * 128;
    const float4 cu = *(const float4*)(bb + (size_t)(t0 + t) * 128 + 64 + 4*p);
    const float4 aa = *(const float4*)(A + 4*p);
    float pw0 = cu.x * S2, pw1 = cu.y * S2, pw2 = cu.z * S2, pw3 = cu.w * S2;
    #pragma unroll
    for (int j = 0; j < 16; ++j) {
      const int g = t0 + t - j;
      const float4 b4 = (g >= 0) ? *(const float4*)(bb + (size_t)g * 128 + 4*p)
                                 : make_float4(0.f, 0.f, 0.f, 0.f);
      float s = pw0*b4.x + pw1*b4.y + pw2*b4.z + pw3*b4.w;
      s += __shfl_xor(s, 1, 64);
      s += __shfl_xor(s, 2, 64);
      s += __shfl_xor(s, 4, 64);
      s += __shfl_xor(s, 8, 64);
      if (p == 0) KwS[t][j] = s;
      pw0 *= aa.x; pw1 *= aa.y; pw2 *= aa.z; pw3 *= aa.w;
    }
  }
  __syncthreads();
  if (tid < 64) {                               // coalesced 1 KB Kw write
    const int t = tid >> 2, jq = tid & 3;
    *(float4*)(Kwg + ((size_t)b * LS + t0 + t) * 16 + 4*jq) =
        *(const float4*)&KwS[t][4*jq];
  }
}

// ---------------------------------------------------------------------------
// KC v5 (R6-proven, verbatim): conv(W=16) + u*D + RMSNorm from u + Kw only.
// 512 blocks x 512 thr (2/CU), t-tile 16, ~2 KB LDS.
// ---------------------------------------------------------------------------
__global__ __launch_bounds__(512) void kc(const float* __restrict__ u,
                                          const float* __restrict__ Kwg,
                                          const float* __restrict__ Dv,
                                          const float* __restrict__ nw,
                                          float* __restrict__ out) {
  const int wg = blockIdx.x;                    // 0..511
  const int sw = (wg & 7) * 64 + (wg >> 3);     // chunked XCD swizzle
  const int b  = sw >> 7;
  const int t0 = (sw & 127) * 16;
  const int tid  = threadIdx.x;
  const int lane = tid & 63;
  const int w    = tid >> 6;
  const float* ub = u + (size_t)b * DM * LS;
  float* ob = out + (size_t)b * DM * LS;

  __shared__ float KwS[16][20];
  __shared__ float SSr[8][16];
  __shared__ float rsqv[16];

  if (tid < 64) {                               // stage Kw tile (1 KB, coalesced)
    const int t = tid >> 2, jq = tid & 3;
    *(float4*)&KwS[t][4*jq] =
        *(const float4*)(Kwg + ((size_t)b * LS + t0 + t) * 16 + 4*jq);
  }
  __syncthreads();

  // ---- conv + u*D, y in registers ----
  const int tg = tid & 3;
  const int dr = tid >> 2;                      // 0..127
  const int cbase = t0 - 16 + 4*tg;
  float y[8][4];
  float ps[4] = {0.f, 0.f, 0.f, 0.f};
  #pragma unroll 1
  for (int c = 0; c < 8; ++c) {
    const int d = dr + 128*c;
    const float* rowp = ub + (size_t)d * LS;
    float wr[20];
    #pragma unroll
    for (int s5 = 0; s5 < 5; ++s5) {
      int g = cbase + 4*s5;
      float4 v = (g >= 0) ? *(const float4*)(rowp + g)
                          : make_float4(0.f, 0.f, 0.f, 0.f);
      wr[4*s5+0] = v.x; wr[4*s5+1] = v.y; wr[4*s5+2] = v.z; wr[4*s5+3] = v.w;
    }
    const float Dd = Dv[d];
    #pragma unroll
    for (int k = 0; k < 4; ++k) {
      f32x4 kv0 = *(const f32x4*)&KwS[4*tg + k][0];   // broadcast b128 reads
      f32x4 kv1 = *(const f32x4*)&KwS[4*tg + k][4];
      f32x4 kv2 = *(const f32x4*)&KwS[4*tg + k][8];
      f32x4 kv3 = *(const f32x4*)&KwS[4*tg + k][12];
      float acc = wr[16 + k] * Dd;                    // skip connection u*D
      #pragma unroll
      for (int j = 0; j < 4; ++j)  acc = fmaf(kv0[j], wr[16 + k - j],      acc);
      #pragma unroll
      for (int j = 0; j < 4; ++j)  acc = fmaf(kv1[j], wr[16 + k - (j+4)],  acc);
      #pragma unroll
      for (int j = 0; j < 4; ++j)  acc = fmaf(kv2[j], wr[16 + k - (j+8)],  acc);
      #pragma unroll
      for (int j = 0; j < 4; ++j)  acc = fmaf(kv3[j], wr[16 + k - (j+12)], acc);
      y[c][k] = acc;
      ps[k] = fmaf(acc, acc, ps[k]);
    }
  }

  // ---- RMS reduce over d ----
  #pragma unroll
  for (int k = 0; k < 4; ++k) {
    ps[k] += __shfl_xor(ps[k], 4, 64);
    ps[k] += __shfl_xor(ps[k], 8, 64);
    ps[k] += __shfl_xor(ps[k], 16, 64);
    ps[k] += __shfl_xor(ps[k], 32, 64);
  }
  if (lane < 4)                                 // lane == tg holds t = 4*lane+k
    *(float4*)&SSr[w][4*lane] = make_float4(ps[0], ps[1], ps[2], ps[3]);
  __syncthreads();
  if (tid < 16) {
    float s = 0.f;
    #pragma unroll
    for (int ww = 0; ww < 8; ++ww) s += SSr[ww][tid];
    rsqv[tid] = rsqrtf(s * (1.f/1024.f) + RMS_EPS);
  }
  __syncthreads();

  // ---- normalize + store ----
  float rq[4];
  #pragma unroll
  for (int k = 0; k < 4; ++k) rq[k] = rsqv[4*tg + k];
  #pragma unroll 1
  for (int c = 0; c < 8; ++c) {
    const int d = dr + 128*c;
    const float wn2 = nw[d];
    float4 o;
    o.x = y[c][0] * rq[0] * wn2;
    o.y = y[c][1] * rq[1] * wn2;
    o.z = y[c][2] * rq[2] * wn2;
    o.w = y[c][3] * rq[3] * wn2;
    *(float4*)(ob + (size_t)d * LS + t0 + 4*tg) = o;
  }
}

// ---------------------------------------------------------------------------
extern "C" void kernel_launch(void* const* d_in, const int* in_sizes, int n_in,
                              void* d_out, int out_size, void* d_ws, size_t ws_size,
                              hipStream_t stream) {
  // inputs: [0]=L(int,1), [1]=u, [2]=A, [3]=B, [4]=C, [5]=D, [6]=norm_w
  const float* u  = (const float*)d_in[1];
  const float* A  = (const float*)d_in[2];
  const float* B  = (const float*)d_in[3];
  const float* C  = (const float*)d_in[4];
  const float* Dv = (const float*)d_in[5];
  const float* nw = (const float*)d_in[6];
  float* out = (float*)d_out;

  // workspace carve (4.75 MB total)
  float* BuCuT = (float*)d_ws;                                          // 4 MB
  unsigned short* Bbf = (unsigned short*)((char*)d_ws + (4u << 20));    // 256 KB
  float* Kwg = (float*)((char*)d_ws + (4u << 20) + (256u << 10));       // 512 KB

  k0_prep<<<dim3(128),    dim3(256), 0, stream>>>(B, C, Bbf);
  k1_gemm<<<dim3(128, 4), dim3(256), 0, stream>>>(u, Bbf, BuCuT);
  kwx    <<<dim3(128, 4), dim3(256), 0, stream>>>(BuCuT, A, Kwg);
  kc     <<<dim3(512),    dim3(512), 0, stream>>>(u, Kwg, Dv, nw, out);
}